// Round 12
// baseline (2635.793 us; speedup 1.0000x reference)
//
#include <hip/hip_runtime.h>
#include <math.h>
#include <float.h>

// Problem constants (from reference)
#define NB 2
#define LQ 2048
#define HH 8
#define EE 64
#define SS 2048
#define CC 256
#define KM_ITERS 10
#define NBITS 32
#define TK 32
#define NH (NB*HH)

// ---------------- K1: hash bits -> 32-bit mask per (n,h,l) ----------------
__global__ __launch_bounds__(256) void k_hash(const float* __restrict__ Q,
                                              const float* __restrict__ planes,
                                              unsigned int* __restrict__ qmask) {
    int gid = blockIdx.x * 256 + threadIdx.x;      // nh*LQ + l
    int nh = gid >> 11, l = gid & (LQ - 1);
    int n = nh >> 3, h = nh & 7;
    const float* qrow = Q + (((size_t)n * LQ + l) * HH + h) * EE;
    float q[64];
    #pragma unroll
    for (int e = 0; e < 64; e++) q[e] = qrow[e];
    unsigned int m = 0;
    for (int b = 0; b < NBITS; b++) {
        double acc = (double)planes[b * 65 + 64];   // bias
        #pragma unroll
        for (int e = 0; e < 64; e++) acc += (double)q[e] * (double)planes[b * 65 + e];
        if (acc > 0.0) m |= (1u << b);
    }
    qmask[gid] = m;
}

// ---------------- K2a: centroid init ----------------
__global__ __launch_bounds__(256) void k_cinit(const unsigned int* __restrict__ qmask,
                                               unsigned int* __restrict__ cent_g) {
    int nh = blockIdx.x, t = threadIdx.x;
    cent_g[nh * CC + t] = qmask[(size_t)nh * LQ + t * 8];   // init_idx = c*8
}

// ---------------- K2b: assign (data-parallel, 128 blocks) ----------------
__global__ __launch_bounds__(256) void k_assign(const unsigned int* __restrict__ qmask,
                                                const unsigned int* __restrict__ cent_g,
                                                int* __restrict__ asg) {
    int nh = blockIdx.x >> 3;              // 8 blocks per nh
    int p = ((blockIdx.x & 7) << 8) + threadIdx.x;
    int t = threadIdx.x;
    __shared__ __align__(16) unsigned int cent[CC];
    cent[t] = cent_g[nh * CC + t];
    __syncthreads();
    unsigned int m = qmask[(size_t)nh * LQ + p];
    int best = 0x7fffffff;
    const uint4* c4p = (const uint4*)cent;
    #pragma unroll 4
    for (int c4 = 0; c4 < CC / 4; c4++) {
        uint4 cm = c4p[c4];
        int base = c4 << 2;
        int e0 = (__popc(m ^ cm.x) << 8) + base;
        int e1 = (__popc(m ^ cm.y) << 8) + base + 1;
        int e2 = (__popc(m ^ cm.z) << 8) + base + 2;
        int e3 = (__popc(m ^ cm.w) << 8) + base + 3;
        int e01 = e0 < e1 ? e0 : e1;
        int e23 = e2 < e3 ? e2 : e3;
        int e = e01 < e23 ? e01 : e23;
        best = best < e ? best : e;
    }
    asg[(size_t)nh * LQ + p] = best & 255;
}

// ---------------- K2c: update (per-nh counting sort + exact majority) ----------------
__global__ __launch_bounds__(512) void k_update(const unsigned int* __restrict__ qmask,
                                                const int* __restrict__ asg,
                                                unsigned int* __restrict__ cent_g) {
    int nh = blockIdx.x, t = threadIdx.x;
    __shared__ unsigned int sorted[LQ];               // 8KB
    __shared__ int cnts[CC], offs[CC], cursor[CC];
    if (t < CC) cnts[t] = 0;
    int bc[4]; unsigned int mym[4];
    #pragma unroll
    for (int k = 0; k < 4; k++) {
        bc[k] = asg[(size_t)nh * LQ + t + k * 512];
        mym[k] = qmask[(size_t)nh * LQ + t + k * 512];
    }
    __syncthreads();
    #pragma unroll
    for (int k = 0; k < 4; k++) atomicAdd(&cnts[bc[k]], 1);
    __syncthreads();
    if (t < 64) {                                     // single-wave exclusive scan
        int c0 = cnts[4 * t], c1 = cnts[4 * t + 1], c2 = cnts[4 * t + 2], c3 = cnts[4 * t + 3];
        int s1 = c0 + c1, s2 = s1 + c2, tot = s2 + c3;
        int inc = tot;
        #pragma unroll
        for (int o = 1; o < 64; o <<= 1) {
            int v = __shfl_up(inc, o);
            if (t >= o) inc += v;
        }
        int excl = inc - tot;
        offs[4 * t] = excl;          cursor[4 * t] = excl;
        offs[4 * t + 1] = excl + c0; cursor[4 * t + 1] = excl + c0;
        offs[4 * t + 2] = excl + s1; cursor[4 * t + 2] = excl + s1;
        offs[4 * t + 3] = excl + s2; cursor[4 * t + 3] = excl + s2;
    }
    __syncthreads();
    int cl = t >> 1, j = t & 1;
    int cnt_c = cnts[cl], off_c = offs[cl];
    #pragma unroll
    for (int k = 0; k < 4; k++) {
        int pos = atomicAdd(&cursor[bc[k]], 1);
        sorted[pos] = mym[k];
    }
    __syncthreads();
    int bs[32];
    #pragma unroll
    for (int b = 0; b < 32; b++) bs[b] = 0;
    for (int i = j; i < cnt_c; i += 2) {
        unsigned int m = sorted[off_c + i];
        #pragma unroll
        for (int b = 0; b < 32; b++) bs[b] += (m >> b) & 1;
    }
    #pragma unroll
    for (int b = 0; b < 32; b++) bs[b] += __shfl_xor(bs[b], 1);
    if (j == 0 && cnt_c > 0) {
        unsigned int nc = 0;
        #pragma unroll
        for (int b = 0; b < 32; b++) if (2 * bs[b] >= cnt_c) nc |= (1u << b);
        cent_g[nh * CC + cl] = nc;                    // exact majority; keep old if cnt==0
    }
}

// ---------------- K2d: finalize counts/offsets/order from final assignment ----------------
__global__ __launch_bounds__(512) void k_finalize(const int* __restrict__ asg,
                                                  int* __restrict__ counts_out,
                                                  int* __restrict__ order_out,
                                                  int* __restrict__ offsets_out) {
    int nh = blockIdx.x, t = threadIdx.x;
    __shared__ int cnts[CC], offs[CC], cursor[CC];
    if (t < CC) cnts[t] = 0;
    int bc[4];
    #pragma unroll
    for (int k = 0; k < 4; k++) bc[k] = asg[(size_t)nh * LQ + t + k * 512];
    __syncthreads();
    #pragma unroll
    for (int k = 0; k < 4; k++) atomicAdd(&cnts[bc[k]], 1);
    __syncthreads();
    if (t < 64) {
        int c0 = cnts[4 * t], c1 = cnts[4 * t + 1], c2 = cnts[4 * t + 2], c3 = cnts[4 * t + 3];
        int s1 = c0 + c1, s2 = s1 + c2, tot = s2 + c3;
        int inc = tot;
        #pragma unroll
        for (int o = 1; o < 64; o <<= 1) {
            int v = __shfl_up(inc, o);
            if (t >= o) inc += v;
        }
        int excl = inc - tot;
        offs[4 * t] = excl;          cursor[4 * t] = excl;
        offs[4 * t + 1] = excl + c0; cursor[4 * t + 1] = excl + c0;
        offs[4 * t + 2] = excl + s1; cursor[4 * t + 2] = excl + s1;
        offs[4 * t + 3] = excl + s2; cursor[4 * t + 3] = excl + s2;
    }
    __syncthreads();
    if (t < CC) {
        counts_out[nh * CC + t] = cnts[t];
        offsets_out[nh * CC + t] = offs[t];
    }
    #pragma unroll
    for (int k = 0; k < 4; k++) {
        int pos = atomicAdd(&cursor[bc[k]], 1);
        order_out[(size_t)nh * LQ + pos] = t + k * 512;
    }
}

// ---------------- K3: segmented cluster-mean Qg (f64), wave per cluster ----------------
__global__ __launch_bounds__(256) void k_qg(const float* __restrict__ Q,
                                            const int* __restrict__ order,
                                            const int* __restrict__ offsets,
                                            const int* __restrict__ counts,
                                            double* __restrict__ Qg) {
    int nh = blockIdx.x >> 6;              // 64 blocks per nh
    int c = (blockIdx.x & 63) * 4 + (threadIdx.x >> 6);
    int e = threadIdx.x & 63;
    int n = nh >> 3, h = nh & 7;
    int off = offsets[nh * CC + c];
    int cnt = counts[nh * CC + c];
    const int* ord = order + (size_t)nh * LQ + off;
    double acc = 0.0;
    for (int i = 0; i < cnt; i++) {
        int p = ord[i];                    // wave-uniform broadcast read
        acc += (double)Q[(((size_t)n * LQ + p) * HH + h) * EE + e];
    }
    double safe = cnt > 0 ? (double)cnt : 1.0;
    Qg[((size_t)(nh * CC + c)) * EE + e] = acc / safe;
}

// ---------------- K3b: transpose [n][s][h][e] -> [nh][e][s] ----------------
__global__ __launch_bounds__(256) void k_transpose(const float* __restrict__ Xp,
                                                   float* __restrict__ Xt) {
    int nh = blockIdx.x >> 5;              // 32 s-tiles of 64
    int s0 = (blockIdx.x & 31) * 64;
    int n = nh >> 3, h = nh & 7;
    __shared__ float tile[64][65];
    int t = threadIdx.x;
    int e = t & 63, r0 = t >> 6;
    #pragma unroll
    for (int j = 0; j < 16; j++) {
        int r = r0 * 16 + j;
        tile[r][e] = Xp[(((size_t)n * SS + s0 + r) * HH + h) * EE + e];
    }
    __syncthreads();
    int sl = t & 63, eg = t >> 6;
    #pragma unroll
    for (int j = 0; j < 16; j++) {
        int ee_ = eg * 16 + j;
        Xt[((size_t)nh * EE + ee_) * SS + s0 + sl] = tile[sl][ee_];
    }
}

// ---------------- K3c: max_s ||K_s||^2 per nh (from Kt, coalesced) ----------------
__global__ __launch_bounds__(512) void k_knorm(const float* __restrict__ Kt,
                                               unsigned int* __restrict__ Knorm2) {
    int nh = blockIdx.x >> 2;
    int s = ((blockIdx.x & 3) << 9) + threadIdx.x;
    const float* kc = Kt + ((size_t)nh * EE) * SS + s;
    float acc = 0.f;
    for (int e = 0; e < EE; e++) { float kv = kc[(size_t)e * SS]; acc += kv * kv; }
    #pragma unroll
    for (int o = 32; o > 0; o >>= 1) { float z = __shfl_xor(acc, o); acc = z > acc ? z : acc; }
    __shared__ float red[8];
    int w = threadIdx.x >> 6, l = threadIdx.x & 63;
    if (l == 0) red[w] = acc;
    __syncthreads();
    if (threadIdx.x == 0) {
        float m = red[0];
        #pragma unroll
        for (int i = 1; i < 8; i++) m = red[i] > m ? red[i] : m;
        atomicMax(&Knorm2[nh], __float_as_uint(m));   // nonneg floats: bit order == value order
    }
}

// ---------------- K4 v8: LDS-staged, 2 clusters/wave, 8/block, 512 blocks -----------
// R11 lesson: CW=4 + 80KB LDS = 1 wave/SIMD = latency death. This version stages
// K/V chunks [64e][128s] through one 33KB LDS buffer so all 4 waves share a single
// global stream (block traffic 1MB vs 4MB), keeps vw[2][32]=64 VGPR, and phase C
// assigns each thread a fixed (cluster-pair, e) so Vg accumulates in 2 registers
// with no reduction LDS. All vw indices compile-time (chunk loops unrolled).
// f32 fast path + guarded exact-f64 fallback (cold; re-reads Qg/Kt from global).
// NO occupancy clamp (R7/R9 lesson: clamping spills v[32] -> 2x slower).
__global__ __launch_bounds__(256) void k_rows(const float* __restrict__ Kt,
                                              const float* __restrict__ Vt,
                                              const double* __restrict__ Qg,
                                              const unsigned int* __restrict__ Knorm2,
                                              int* __restrict__ topi,
                                              float* __restrict__ abk,
                                              float* __restrict__ Vg) {
    int bid = blockIdx.x;                  // 512 blocks
    int xcd = bid & 7, idx = bid >> 3;     // XCD-chunked: xcd owns 2 nh slices (L2-local)
    int nh = xcd * 2 + (idx >> 5);
    int c0 = (idx & 31) * 8;               // 8 clusters per block
    int t = threadIdx.x, w = t >> 6, l = t & 63;

    __shared__ float qglf[EE][8];          // 2KB
    __shared__ float kvbuf[8320];          // 33.3KB union: A=[64e][128s], C=[128s][65e pad]
    __shared__ float wbuf[128][10];        // 5.1KB (pad 10 -> aligned float2, odd-ish banks)

    for (int i = t; i < EE * 8; i += 256) {
        int e = i >> 3, c = i & 7;
        qglf[e][c] = (float)Qg[((size_t)(nh * CC + c0 + c)) * EE + e];
    }
    __syncthreads();

    const float* ktbase = Kt + ((size_t)nh * EE) * SS;
    const float* vtbase = Vt + ((size_t)nh * EE) * SS;

    // ---- phase A: staged QK. wave w owns clusters c0+2w, c0+2w+1.
    // lane l owns s = ch*128 + 2l + j  ->  vw[cc][ch*2+j]
    float vw[2][32];
    #pragma unroll
    for (int ch = 0; ch < 16; ch++) {
        #pragma unroll
        for (int j = 0; j < 8; j++) {      // stage K chunk [64][128] = 8192 floats
            int gi = t + j * 256;          // float4 index
            int e = gi >> 5, sq = gi & 31;
            float4 kk = *(const float4*)(ktbase + (size_t)e * SS + ch * 128 + sq * 4);
            *(float4*)&kvbuf[e * 128 + sq * 4] = kk;
        }
        __syncthreads();
        float a00 = 0.f, a01 = 0.f, a10 = 0.f, a11 = 0.f;
        for (int e = 0; e < EE; e++) {
            float2 kp = *(const float2*)&kvbuf[e * 128 + 2 * l];   // 2-way bank alias: free
            float2 qp = *(const float2*)&qglf[e][w * 2];           // wave-uniform broadcast
            a00 += qp.x * kp.x; a01 += qp.x * kp.y;
            a10 += qp.y * kp.x; a11 += qp.y * kp.y;
        }
        vw[0][ch * 2 + 0] = a00; vw[0][ch * 2 + 1] = a01;
        vw[1][ch * 2 + 0] = a10; vw[1][ch * 2 + 1] = a11;
        __syncthreads();
    }

    // ---- per-cluster ||qg||^2 (lane l = e index) ----
    float qn2[2];
    #pragma unroll
    for (int cc = 0; cc < 2; cc++) {
        float qv = qglf[l][w * 2 + cc];
        float s = qv * qv;
        #pragma unroll
        for (int o = 32; o > 0; o >>= 1) s += __shfl_xor(s, o);
        qn2[cc] = s;
    }
    float kn2 = __uint_as_float(Knorm2[nh]);

    // ---- phase B per cluster: max, denom, top-32, guard, weights in place ----
    #pragma unroll
    for (int cc = 0; cc < 2; cc++) {
        int rowid = nh * CC + c0 + w * 2 + cc;
        float mf = vw[cc][0];
        #pragma unroll
        for (int k = 1; k < 32; k++) mf = vw[cc][k] > mf ? vw[cc][k] : mf;
        #pragma unroll
        for (int o = 32; o > 0; o >>= 1) { float z = __shfl_xor(mf, o); mf = z > mf ? z : mf; }

        float ds = 0.f;
        #pragma unroll
        for (int k = 0; k < 32; k++) ds += expf(0.125f * (vw[cc][k] - mf));
        #pragma unroll
        for (int o = 32; o > 0; o >>= 1) ds += __shfl_xor(ds, o);

        unsigned ext = 0u;
        float lbv = -3.0e38f; int lbi = 1 << 30;
        #pragma unroll
        for (int k = 0; k < 32; k++)
            if (vw[cc][k] > lbv) { lbv = vw[cc][k]; lbi = (k >> 1) * 128 + 2 * l + (k & 1); }
        float topsum = 0.f, s32 = 0.f;
        for (int kk = 0; kk < TK; kk++) {
            float bv = lbv; int bi = lbi;
            #pragma unroll
            for (int o = 32; o > 0; o >>= 1) {
                float v2 = __shfl_xor(bv, o); int i2 = __shfl_xor(bi, o);
                if (v2 > bv || (v2 == bv && i2 < bi)) { bv = v2; bi = i2; }
            }
            topsum += expf(0.125f * (bv - mf));
            if (l == 0) topi[(size_t)rowid * TK + kk] = bi;
            if (kk == TK - 1) s32 = bv;
            if (((bi & 127) >> 1) == l) {  // this lane owned the winner
                ext |= 1u << (((bi >> 7) << 1) | (bi & 1));
                lbv = -3.0e38f; lbi = 1 << 30;
                #pragma unroll
                for (int k = 0; k < 32; k++)
                    if (!((ext >> k) & 1) && vw[cc][k] > lbv) { lbv = vw[cc][k]; lbi = (k >> 1) * 128 + 2 * l + (k & 1); }
            }
        }
        float s33;
        {
            float bv = lbv; int bi = lbi;
            #pragma unroll
            for (int o = 32; o > 0; o >>= 1) {
                float v2 = __shfl_xor(bv, o); int i2 = __shfl_xor(bi, o);
                if (v2 > bv || (v2 == bv && i2 < bi)) { bv = v2; bi = i2; }
            }
            s33 = bv;
        }
        float eps2 = 1.6e-5f * sqrtf(qn2[cc] * kn2);

        if (s32 - s33 < eps2) {
            // ---------- cold f64 fallback: exact recompute of this row ----------
            double v64[32];
            #pragma unroll
            for (int k = 0; k < 32; k++) v64[k] = 0.0;
            for (int e = 0; e < EE; e++) {
                double qe = Qg[(size_t)rowid * EE + e];            // wave-uniform
                const float* krow = ktbase + (size_t)e * SS;
                #pragma unroll
                for (int ch = 0; ch < 16; ch++) {
                    float2 kp = *(const float2*)&krow[ch * 128 + 2 * l];
                    v64[ch * 2 + 0] += qe * (double)kp.x;
                    v64[ch * 2 + 1] += qe * (double)kp.y;
                }
            }
            double m64 = v64[0];
            #pragma unroll
            for (int k = 1; k < 32; k++) m64 = v64[k] > m64 ? v64[k] : m64;
            #pragma unroll
            for (int o = 32; o > 0; o >>= 1) { double z = __shfl_xor(m64, o); m64 = z > m64 ? z : m64; }
            double ds64 = 0.0;
            #pragma unroll
            for (int k = 0; k < 32; k++) ds64 += (double)expf(0.125f * (float)(v64[k] - m64));
            #pragma unroll
            for (int o = 32; o > 0; o >>= 1) ds64 += __shfl_xor(ds64, o);
            unsigned ex2 = 0u;
            double lb = -1e301; int li = 1 << 30;
            #pragma unroll
            for (int k = 0; k < 32; k++)
                if (v64[k] > lb) { lb = v64[k]; li = (k >> 1) * 128 + 2 * l + (k & 1); }
            double ts64 = 0.0;
            for (int kk = 0; kk < TK; kk++) {
                double bv = lb; int bi = li;
                #pragma unroll
                for (int o = 32; o > 0; o >>= 1) {
                    double v2 = __shfl_xor(bv, o); int i2 = __shfl_xor(bi, o);
                    if (v2 > bv || (v2 == bv && i2 < bi)) { bv = v2; bi = i2; }
                }
                ts64 += (double)expf(0.125f * (float)(bv - m64));
                if (l == 0) topi[(size_t)rowid * TK + kk] = bi;
                if (((bi & 127) >> 1) == l) {
                    ex2 |= 1u << (((bi >> 7) << 1) | (bi & 1));
                    lb = -1e301; li = 1 << 30;
                    #pragma unroll
                    for (int k = 0; k < 32; k++)
                        if (!((ex2 >> k) & 1) && v64[k] > lb) { lb = v64[k]; li = (k >> 1) * 128 + 2 * l + (k & 1); }
                }
            }
            if (l == 0) abk[rowid] = (float)((ds64 - ts64) / ds64);
            float invd = (float)(1.0 / ds64);
            #pragma unroll
            for (int k = 0; k < 32; k++)
                vw[cc][k] = ((ex2 >> k) & 1) ? 0.0f
                          : expf(0.125f * (float)(v64[k] - m64)) * invd;
        } else {
            if (l == 0) abk[rowid] = (ds - topsum) / ds;
            float invd = 1.0f / ds;
            #pragma unroll
            for (int k = 0; k < 32; k++)
                vw[cc][k] = ((ext >> k) & 1) ? 0.0f
                          : expf(0.125f * (vw[cc][k] - mf)) * invd;
        }
    }

    // ---- phase C: staged PV. thread owns (cluster-pair cg, e); acc in 2 regs ----
    float acc0 = 0.f, acc1 = 0.f;
    int e_c = t & 63, cg = t >> 6;         // clusters c0 + cg*2 + {0,1}
    #pragma unroll
    for (int ch = 0; ch < 16; ch++) {
        // weights for this chunk into wbuf[s][c] (wave w, its 2 clusters)
        #pragma unroll
        for (int cc = 0; cc < 2; cc++) {
            wbuf[2 * l + 0][w * 2 + cc] = vw[cc][ch * 2 + 0];
            wbuf[2 * l + 1][w * 2 + cc] = vw[cc][ch * 2 + 1];
        }
        #pragma unroll
        for (int j = 0; j < 8; j++) {      // stage V chunk transposed [128s][65e]
            int gi = t + j * 256;
            int e = gi >> 5, sq = gi & 31;
            float4 vv = *(const float4*)(vtbase + (size_t)e * SS + ch * 128 + sq * 4);
            kvbuf[(sq * 4 + 0) * 65 + e] = vv.x;
            kvbuf[(sq * 4 + 1) * 65 + e] = vv.y;
            kvbuf[(sq * 4 + 2) * 65 + e] = vv.z;
            kvbuf[(sq * 4 + 3) * 65 + e] = vv.w;
        }
        __syncthreads();
        for (int s = 0; s < 128; s++) {
            float vv = kvbuf[s * 65 + e_c];                        // conflict-free
            float2 wp = *(const float2*)&wbuf[s][cg * 2];          // wave-uniform broadcast
            acc0 += wp.x * vv; acc1 += wp.y * vv;
        }
        __syncthreads();
    }
    Vg[((size_t)(nh * CC + c0 + cg * 2 + 0)) * EE + e_c] = acc0;
    Vg[((size_t)(nh * CC + c0 + cg * 2 + 1)) * EE + e_c] = acc1;
}

// ---------------- K5: per-query top-32 re-attention + V_bottom ----------------
__global__ __launch_bounds__(256) void k_out(const float* __restrict__ Q,
                                             const float* __restrict__ Kp,
                                             const float* __restrict__ Vp,
                                             const int* __restrict__ clusters,
                                             const int* __restrict__ topi,
                                             const float* __restrict__ abk,
                                             const float* __restrict__ Vg,
                                             float* __restrict__ out) {
    int tid = threadIdx.x, wid = tid >> 6, e = tid & 63;
    int q = blockIdx.x * 4 + wid;            // nh*LQ + l
    int nh = q >> 11, l = q & (LQ - 1);
    int n = nh >> 3, h = nh & 7;
    int c = clusters[q];
    float scale = 1.0f - abk[nh * CC + c];
    const int* ti = topi + (size_t)(nh * CC + c) * TK;
    float qe = Q[(((size_t)n * LQ + l) * HH + h) * EE + e];
    float myv = -INFINITY;
    for (int k = 0; k < TK; k++) {
        int idx = ti[k];
        float kv = Kp[(((size_t)n * SS + idx) * HH + h) * EE + e];
        float v = qe * kv;
        #pragma unroll
        for (int o = 32; o > 0; o >>= 1) v += __shfl_xor(v, o);
        if (e == k) myv = v;
    }
    float mv = myv;
    #pragma unroll
    for (int o = 32; o > 0; o >>= 1) { float v = __shfl_xor(mv, o); mv = v > mv ? v : mv; }
    float p = (e < TK) ? expf(0.125f * (myv - mv)) : 0.0f;
    float ssum = p;
    #pragma unroll
    for (int o = 32; o > 0; o >>= 1) ssum += __shfl_xor(ssum, o);
    float at = p / ssum * scale;
    float acc = 0.0f;
    for (int k = 0; k < TK; k++) {
        float wk = __shfl(at, k, 64);
        int idx = ti[k];
        acc += wk * Vp[(((size_t)n * SS + idx) * HH + h) * EE + e];
    }
    acc += Vg[(size_t)(nh * CC + c) * EE + e];
    out[(((size_t)n * LQ + l) * HH + h) * EE + e] = acc;
}

extern "C" void kernel_launch(void* const* d_in, const int* in_sizes, int n_in,
                              void* d_out, int out_size, void* d_ws, size_t ws_size,
                              hipStream_t stream) {
    const float* Q      = (const float*)d_in[0];
    const float* K      = (const float*)d_in[1];
    const float* V      = (const float*)d_in[2];
    const float* planes = (const float*)d_in[3];
    float* out = (float*)d_out;

    char* ws = (char*)d_ws;
    unsigned int* qmask    = (unsigned int*)(ws);                   // 128KB
    int*          clusters = (int*)(ws + (128 << 10));              // 128KB (= asg)
    int*          counts   = (int*)(ws + (256 << 10));              // 16KB
    float*        abk      = (float*)(ws + (272 << 10));            // 16KB
    int*          topi     = (int*)(ws + (288 << 10));              // 512KB
    float*        Vg       = (float*)(ws + (800 << 10));            // 1MB
    double*       Qg       = (double*)(ws + (1824 << 10));          // 2MB
    float*        Kt       = (float*)(ws + (4096 << 10));           // 8MB  [4MB,12MB)
    int*          order    = (int*)(ws + (12288 << 10));            // 128KB
    int*          offsets  = (int*)(ws + (12416 << 10));            // 16KB
    unsigned int* cent_g   = (unsigned int*)(ws + (12432 << 10));   // 16KB
    unsigned int* Knorm2   = (unsigned int*)(ws + (12448 << 10));   // 64B
    float*        Vt       = (float*)(ws + (12544 << 10));          // 8MB [12.25MB,20.25MB)

    hipMemsetAsync(Knorm2, 0, NH * sizeof(unsigned int), stream);
    k_transpose<<<dim3(NH * 32), dim3(256), 0, stream>>>(K, Kt);
    k_transpose<<<dim3(NH * 32), dim3(256), 0, stream>>>(V, Vt);
    k_knorm<<<dim3(NH * 4), dim3(512), 0, stream>>>(Kt, Knorm2);
    k_hash<<<dim3(NH * LQ / 256), dim3(256), 0, stream>>>(Q, planes, qmask);
    k_cinit<<<dim3(NH), dim3(256), 0, stream>>>(qmask, cent_g);
    for (int it = 0; it < KM_ITERS; ++it) {
        k_assign<<<dim3(NH * 8), dim3(256), 0, stream>>>(qmask, cent_g, clusters);
        k_update<<<dim3(NH), dim3(512), 0, stream>>>(qmask, clusters, cent_g);
    }
    k_assign<<<dim3(NH * 8), dim3(256), 0, stream>>>(qmask, cent_g, clusters);
    k_finalize<<<dim3(NH), dim3(512), 0, stream>>>(clusters, counts, order, offsets);
    k_qg<<<dim3(NH * 64), dim3(256), 0, stream>>>(Q, order, offsets, counts, Qg);
    k_rows<<<dim3(NH * CC / 8), dim3(256), 0, stream>>>(Kt, Vt, Qg, Knorm2, topi, abk, Vg);
    k_out<<<dim3(NH * LQ / 4), dim3(256), 0, stream>>>(Q, K, V, clusters, topi, abk, Vg, out);
}

// Round 13
// 445.167 us; speedup vs baseline: 5.9209x; 5.9209x over previous
//
#include <hip/hip_runtime.h>
#include <math.h>
#include <float.h>

// Problem constants (from reference)
#define NB 2
#define LQ 2048
#define HH 8
#define EE 64
#define SS 2048
#define CC 256
#define KM_ITERS 10
#define NBITS 32
#define TK 32
#define NH (NB*HH)
#define CG 4    // clusters per k_rows block

// ---------------- K1: hash bits -> 32-bit mask per (n,h,l) ----------------
__global__ __launch_bounds__(256) void k_hash(const float* __restrict__ Q,
                                              const float* __restrict__ planes,
                                              unsigned int* __restrict__ qmask) {
    int gid = blockIdx.x * 256 + threadIdx.x;      // nh*LQ + l
    int nh = gid >> 11, l = gid & (LQ - 1);
    int n = nh >> 3, h = nh & 7;
    const float* qrow = Q + (((size_t)n * LQ + l) * HH + h) * EE;
    float q[64];
    #pragma unroll
    for (int e = 0; e < 64; e++) q[e] = qrow[e];
    unsigned int m = 0;
    for (int b = 0; b < NBITS; b++) {
        double acc = (double)planes[b * 65 + 64];   // bias
        #pragma unroll
        for (int e = 0; e < 64; e++) acc += (double)q[e] * (double)planes[b * 65 + e];
        if (acc > 0.0) m |= (1u << b);
    }
    qmask[gid] = m;
}

// ---------------- K2a: centroid init ----------------
__global__ __launch_bounds__(256) void k_cinit(const unsigned int* __restrict__ qmask,
                                               unsigned int* __restrict__ cent_g) {
    int nh = blockIdx.x, t = threadIdx.x;
    cent_g[nh * CC + t] = qmask[(size_t)nh * LQ + t * 8];   // init_idx = c*8
}

// ---------------- K2b: assign (data-parallel, 128 blocks) ----------------
__global__ __launch_bounds__(256) void k_assign(const unsigned int* __restrict__ qmask,
                                                const unsigned int* __restrict__ cent_g,
                                                int* __restrict__ asg) {
    int nh = blockIdx.x >> 3;              // 8 blocks per nh
    int p = ((blockIdx.x & 7) << 8) + threadIdx.x;
    int t = threadIdx.x;
    __shared__ __align__(16) unsigned int cent[CC];
    cent[t] = cent_g[nh * CC + t];
    __syncthreads();
    unsigned int m = qmask[(size_t)nh * LQ + p];
    int best = 0x7fffffff;
    const uint4* c4p = (const uint4*)cent;
    #pragma unroll 4
    for (int c4 = 0; c4 < CC / 4; c4++) {
        uint4 cm = c4p[c4];
        int base = c4 << 2;
        int e0 = (__popc(m ^ cm.x) << 8) + base;
        int e1 = (__popc(m ^ cm.y) << 8) + base + 1;
        int e2 = (__popc(m ^ cm.z) << 8) + base + 2;
        int e3 = (__popc(m ^ cm.w) << 8) + base + 3;
        int e01 = e0 < e1 ? e0 : e1;
        int e23 = e2 < e3 ? e2 : e3;
        int e = e01 < e23 ? e01 : e23;
        best = best < e ? best : e;
    }
    asg[(size_t)nh * LQ + p] = best & 255;
}

// ---------------- K2c: update (per-nh counting sort + exact majority) ----------------
__global__ __launch_bounds__(512) void k_update(const unsigned int* __restrict__ qmask,
                                                const int* __restrict__ asg,
                                                unsigned int* __restrict__ cent_g) {
    int nh = blockIdx.x, t = threadIdx.x;
    __shared__ unsigned int sorted[LQ];               // 8KB
    __shared__ int cnts[CC], offs[CC], cursor[CC];
    if (t < CC) cnts[t] = 0;
    int bc[4]; unsigned int mym[4];
    #pragma unroll
    for (int k = 0; k < 4; k++) {
        bc[k] = asg[(size_t)nh * LQ + t + k * 512];
        mym[k] = qmask[(size_t)nh * LQ + t + k * 512];
    }
    __syncthreads();
    #pragma unroll
    for (int k = 0; k < 4; k++) atomicAdd(&cnts[bc[k]], 1);
    __syncthreads();
    if (t < 64) {                                     // single-wave exclusive scan
        int c0 = cnts[4 * t], c1 = cnts[4 * t + 1], c2 = cnts[4 * t + 2], c3 = cnts[4 * t + 3];
        int s1 = c0 + c1, s2 = s1 + c2, tot = s2 + c3;
        int inc = tot;
        #pragma unroll
        for (int o = 1; o < 64; o <<= 1) {
            int v = __shfl_up(inc, o);
            if (t >= o) inc += v;
        }
        int excl = inc - tot;
        offs[4 * t] = excl;          cursor[4 * t] = excl;
        offs[4 * t + 1] = excl + c0; cursor[4 * t + 1] = excl + c0;
        offs[4 * t + 2] = excl + s1; cursor[4 * t + 2] = excl + s1;
        offs[4 * t + 3] = excl + s2; cursor[4 * t + 3] = excl + s2;
    }
    __syncthreads();
    int cl = t >> 1, j = t & 1;
    int cnt_c = cnts[cl], off_c = offs[cl];
    #pragma unroll
    for (int k = 0; k < 4; k++) {
        int pos = atomicAdd(&cursor[bc[k]], 1);
        sorted[pos] = mym[k];
    }
    __syncthreads();
    int bs[32];
    #pragma unroll
    for (int b = 0; b < 32; b++) bs[b] = 0;
    for (int i = j; i < cnt_c; i += 2) {
        unsigned int m = sorted[off_c + i];
        #pragma unroll
        for (int b = 0; b < 32; b++) bs[b] += (m >> b) & 1;
    }
    #pragma unroll
    for (int b = 0; b < 32; b++) bs[b] += __shfl_xor(bs[b], 1);
    if (j == 0 && cnt_c > 0) {
        unsigned int nc = 0;
        #pragma unroll
        for (int b = 0; b < 32; b++) if (2 * bs[b] >= cnt_c) nc |= (1u << b);
        cent_g[nh * CC + cl] = nc;                    // exact majority; keep old if cnt==0
    }
}

// ---------------- K2d: finalize counts/offsets/order from final assignment ----------------
__global__ __launch_bounds__(512) void k_finalize(const int* __restrict__ asg,
                                                  int* __restrict__ counts_out,
                                                  int* __restrict__ order_out,
                                                  int* __restrict__ offsets_out) {
    int nh = blockIdx.x, t = threadIdx.x;
    __shared__ int cnts[CC], offs[CC], cursor[CC];
    if (t < CC) cnts[t] = 0;
    int bc[4];
    #pragma unroll
    for (int k = 0; k < 4; k++) bc[k] = asg[(size_t)nh * LQ + t + k * 512];
    __syncthreads();
    #pragma unroll
    for (int k = 0; k < 4; k++) atomicAdd(&cnts[bc[k]], 1);
    __syncthreads();
    if (t < 64) {
        int c0 = cnts[4 * t], c1 = cnts[4 * t + 1], c2 = cnts[4 * t + 2], c3 = cnts[4 * t + 3];
        int s1 = c0 + c1, s2 = s1 + c2, tot = s2 + c3;
        int inc = tot;
        #pragma unroll
        for (int o = 1; o < 64; o <<= 1) {
            int v = __shfl_up(inc, o);
            if (t >= o) inc += v;
        }
        int excl = inc - tot;
        offs[4 * t] = excl;          cursor[4 * t] = excl;
        offs[4 * t + 1] = excl + c0; cursor[4 * t + 1] = excl + c0;
        offs[4 * t + 2] = excl + s1; cursor[4 * t + 2] = excl + s1;
        offs[4 * t + 3] = excl + s2; cursor[4 * t + 3] = excl + s2;
    }
    __syncthreads();
    if (t < CC) {
        counts_out[nh * CC + t] = cnts[t];
        offsets_out[nh * CC + t] = offs[t];
    }
    #pragma unroll
    for (int k = 0; k < 4; k++) {
        int pos = atomicAdd(&cursor[bc[k]], 1);
        order_out[(size_t)nh * LQ + pos] = t + k * 512;
    }
}

// ---------------- K3: segmented cluster-mean Qg (f64), wave per cluster ----------------
__global__ __launch_bounds__(256) void k_qg(const float* __restrict__ Q,
                                            const int* __restrict__ order,
                                            const int* __restrict__ offsets,
                                            const int* __restrict__ counts,
                                            double* __restrict__ Qg) {
    int nh = blockIdx.x >> 6;              // 64 blocks per nh
    int c = (blockIdx.x & 63) * 4 + (threadIdx.x >> 6);
    int e = threadIdx.x & 63;
    int n = nh >> 3, h = nh & 7;
    int off = offsets[nh * CC + c];
    int cnt = counts[nh * CC + c];
    const int* ord = order + (size_t)nh * LQ + off;
    double acc = 0.0;
    for (int i = 0; i < cnt; i++) {
        int p = ord[i];                    // wave-uniform broadcast read
        acc += (double)Q[(((size_t)n * LQ + p) * HH + h) * EE + e];
    }
    double safe = cnt > 0 ? (double)cnt : 1.0;
    Qg[((size_t)(nh * CC + c)) * EE + e] = acc / safe;
}

// ---------------- K3b: transpose K -> Kt[nh][e][s] ----------------
__global__ __launch_bounds__(256) void k_transpose(const float* __restrict__ Kp,
                                                   float* __restrict__ Kt) {
    int nh = blockIdx.x >> 5;              // 32 s-tiles of 64
    int s0 = (blockIdx.x & 31) * 64;
    int n = nh >> 3, h = nh & 7;
    __shared__ float tile[64][65];
    int t = threadIdx.x;
    int e = t & 63, r0 = t >> 6;
    #pragma unroll
    for (int j = 0; j < 16; j++) {
        int r = r0 * 16 + j;
        tile[r][e] = Kp[(((size_t)n * SS + s0 + r) * HH + h) * EE + e];
    }
    __syncthreads();
    int sl = t & 63, eg = t >> 6;
    #pragma unroll
    for (int j = 0; j < 16; j++) {
        int ee_ = eg * 16 + j;
        Kt[((size_t)nh * EE + ee_) * SS + s0 + sl] = tile[sl][ee_];
    }
}

// ---------------- K4 v2 (R6 known-best): 4 clusters/block; xrow in LDS; f64 ----------
__global__ __launch_bounds__(256) void k_rows(const float* __restrict__ Kt,
                                              const float* __restrict__ Vp,
                                              const double* __restrict__ Qg,
                                              int* __restrict__ topi,
                                              float* __restrict__ abk,
                                              float* __restrict__ Vg) {
    int bid = blockIdx.x;
    int nh = bid >> 6, cg = bid & 63;
    int c0 = cg * CG;
    int n = nh >> 3, h = nh & 7;
    int t = threadIdx.x, w = t >> 6, l = t & 63;

    __shared__ double xrow[CG][SS];        // 64KB; overlaid later
    __shared__ double qgl[EE][CG];         // 2KB
    float* wpack = (float*)&xrow[0][0];    // [SS][CG] f32 = 32KB (xrow[0..1])
    float* redv  = (float*)&xrow[2][0];    // 4KB (xrow[2] region, disjoint)

    qgl[t >> 2][t & 3] = Qg[((size_t)(nh * CC + c0 + (t & 3))) * EE + (t >> 2)];
    __syncthreads();

    // ---- phase A: QK scores (f64), coalesced Kt reads ----
    double acc[8][CG];
    #pragma unroll
    for (int r = 0; r < 8; r++)
        #pragma unroll
        for (int c = 0; c < CG; c++) acc[r][c] = 0.0;
    const float* ktb = Kt + ((size_t)nh * EE) * SS + t;
    for (int e = 0; e < EE; e++) {
        double q0 = qgl[e][0], q1 = qgl[e][1], q2 = qgl[e][2], q3 = qgl[e][3];
        const float* kr = ktb + (size_t)e * SS;
        #pragma unroll
        for (int r = 0; r < 8; r++) {
            double kv = (double)kr[r * 256];
            acc[r][0] += q0 * kv; acc[r][1] += q1 * kv;
            acc[r][2] += q2 * kv; acc[r][3] += q3 * kv;
        }
    }
    #pragma unroll
    for (int r = 0; r < 8; r++)
        #pragma unroll
        for (int c = 0; c < CG; c++) xrow[c][t + r * 256] = acc[r][c];
    __syncthreads();

    // ---- phase B: per-wave row (c = w): max, denom, top-32, weights ----
    double v[32];
    #pragma unroll
    for (int k = 0; k < 32; k++) v[k] = xrow[w][l + k * 64];

    double m = v[0];
    #pragma unroll
    for (int k = 1; k < 32; k++) m = v[k] > m ? v[k] : m;
    #pragma unroll
    for (int o = 32; o > 0; o >>= 1) { double z = __shfl_xor(m, o); m = z > m ? z : m; }

    double ds = 0.0;
    #pragma unroll
    for (int k = 0; k < 32; k++) ds += (double)expf(0.125f * (float)(v[k] - m));
    #pragma unroll
    for (int o = 32; o > 0; o >>= 1) ds += __shfl_xor(ds, o);

    unsigned ext = 0;
    double lbv = -1e301; int lbi = 1 << 30;
    #pragma unroll
    for (int k = 0; k < 32; k++)
        if (v[k] > lbv) { lbv = v[k]; lbi = l + k * 64; }
    double topsum = 0.0;
    int rowid = nh * CC + c0 + w;
    for (int kk = 0; kk < TK; kk++) {
        double bv = lbv; int bi = lbi;
        #pragma unroll
        for (int o = 32; o > 0; o >>= 1) {
            double v2 = __shfl_xor(bv, o); int i2 = __shfl_xor(bi, o);
            if (v2 > bv || (v2 == bv && i2 < bi)) { bv = v2; bi = i2; }
        }
        topsum += (double)expf(0.125f * (float)(bv - m));
        if (l == 0) topi[(size_t)rowid * TK + kk] = bi;
        if ((bi & 63) == l) {
            ext |= 1u << (bi >> 6);
            lbv = -1e301; lbi = 1 << 30;
            #pragma unroll
            for (int k = 0; k < 32; k++)
                if (!((ext >> k) & 1) && v[k] > lbv) { lbv = v[k]; lbi = l + k * 64; }
        }
    }
    if (l == 0) abk[rowid] = (float)((ds - topsum) / ds);
    __syncthreads();

    float invd = (float)(1.0 / ds);
    #pragma unroll
    for (int k = 0; k < 32; k++) {
        float wk = ((ext >> k) & 1) ? 0.0f
                 : expf(0.125f * (float)(v[k] - m)) * invd;
        wpack[(l + k * 64) * CG + w] = wk;
    }
    __syncthreads();

    // ---- phase C: Vg = W x V, coalesced V reads, f32 accumulate ----
    {
        int e = l, grp = w;
        float a0 = 0, a1 = 0, a2 = 0, a3 = 0;
        const float* vb = Vp + (((size_t)n * SS) * HH + h) * EE + e;
        const float4* wp4 = (const float4*)wpack;
        for (int s = grp * 512; s < grp * 512 + 512; s++) {
            float4 wv = wp4[s];
            float vv = vb[(size_t)s * HH * EE];
            a0 += wv.x * vv; a1 += wv.y * vv; a2 += wv.z * vv; a3 += wv.w * vv;
        }
        redv[(grp * 4 + 0) * 64 + e] = a0;
        redv[(grp * 4 + 1) * 64 + e] = a1;
        redv[(grp * 4 + 2) * 64 + e] = a2;
        redv[(grp * 4 + 3) * 64 + e] = a3;
        __syncthreads();
        int c = w;
        float s = redv[(0 * 4 + c) * 64 + e] + redv[(1 * 4 + c) * 64 + e]
                + redv[(2 * 4 + c) * 64 + e] + redv[(3 * 4 + c) * 64 + e];
        Vg[((size_t)(nh * CC + c0 + c)) * EE + e] = s;
    }
}

// ---------------- K5: per-query top-32 re-attention + V_bottom ----------------
__global__ __launch_bounds__(256) void k_out(const float* __restrict__ Q,
                                             const float* __restrict__ Kp,
                                             const float* __restrict__ Vp,
                                             const int* __restrict__ clusters,
                                             const int* __restrict__ topi,
                                             const float* __restrict__ abk,
                                             const float* __restrict__ Vg,
                                             float* __restrict__ out) {
    int tid = threadIdx.x, wid = tid >> 6, e = tid & 63;
    int q = blockIdx.x * 4 + wid;            // nh*LQ + l
    int nh = q >> 11, l = q & (LQ - 1);
    int n = nh >> 3, h = nh & 7;
    int c = clusters[q];
    float scale = 1.0f - abk[nh * CC + c];
    const int* ti = topi + (size_t)(nh * CC + c) * TK;
    float qe = Q[(((size_t)n * LQ + l) * HH + h) * EE + e];
    float myv = -INFINITY;
    for (int k = 0; k < TK; k++) {
        int idx = ti[k];
        float kv = Kp[(((size_t)n * SS + idx) * HH + h) * EE + e];
        float v = qe * kv;
        #pragma unroll
        for (int o = 32; o > 0; o >>= 1) v += __shfl_xor(v, o);
        if (e == k) myv = v;
    }
    float mv = myv;
    #pragma unroll
    for (int o = 32; o > 0; o >>= 1) { float v = __shfl_xor(mv, o); mv = v > mv ? v : mv; }
    float p = (e < TK) ? expf(0.125f * (myv - mv)) : 0.0f;
    float ssum = p;
    #pragma unroll
    for (int o = 32; o > 0; o >>= 1) ssum += __shfl_xor(ssum, o);
    float at = p / ssum * scale;
    float acc = 0.0f;
    for (int k = 0; k < TK; k++) {
        float wk = __shfl(at, k, 64);
        int idx = ti[k];
        acc += wk * Vp[(((size_t)n * SS + idx) * HH + h) * EE + e];
    }
    acc += Vg[(size_t)(nh * CC + c) * EE + e];
    out[(((size_t)n * LQ + l) * HH + h) * EE + e] = acc;
}

extern "C" void kernel_launch(void* const* d_in, const int* in_sizes, int n_in,
                              void* d_out, int out_size, void* d_ws, size_t ws_size,
                              hipStream_t stream) {
    const float* Q      = (const float*)d_in[0];
    const float* K      = (const float*)d_in[1];
    const float* V      = (const float*)d_in[2];
    const float* planes = (const float*)d_in[3];
    float* out = (float*)d_out;

    char* ws = (char*)d_ws;
    unsigned int* qmask    = (unsigned int*)(ws);                   // 128KB
    int*          clusters = (int*)(ws + (128 << 10));              // 128KB (= asg)
    int*          counts   = (int*)(ws + (256 << 10));              // 16KB
    float*        abk      = (float*)(ws + (272 << 10));            // 16KB
    int*          topi     = (int*)(ws + (288 << 10));              // 512KB
    float*        Vg       = (float*)(ws + (800 << 10));            // 1MB
    double*       Qg       = (double*)(ws + (1824 << 10));          // 2MB
    float*        Kt       = (float*)(ws + (4096 << 10));           // 8MB  [4MB,12MB)
    int*          order    = (int*)(ws + (12288 << 10));            // 128KB
    int*          offsets  = (int*)(ws + (12416 << 10));            // 16KB
    unsigned int* cent_g   = (unsigned int*)(ws + (12432 << 10));   // 16KB

    k_transpose<<<dim3(NH * 32), dim3(256), 0, stream>>>(K, Kt);
    k_hash<<<dim3(NH * LQ / 256), dim3(256), 0, stream>>>(Q, planes, qmask);
    k_cinit<<<dim3(NH), dim3(256), 0, stream>>>(qmask, cent_g);
    for (int it = 0; it < KM_ITERS; ++it) {
        k_assign<<<dim3(NH * 8), dim3(256), 0, stream>>>(qmask, cent_g, clusters);
        k_update<<<dim3(NH), dim3(512), 0, stream>>>(qmask, clusters, cent_g);
    }
    k_assign<<<dim3(NH * 8), dim3(256), 0, stream>>>(qmask, cent_g, clusters);
    k_finalize<<<dim3(NH), dim3(512), 0, stream>>>(clusters, counts, order, offsets);
    k_qg<<<dim3(NH * 64), dim3(256), 0, stream>>>(Q, order, offsets, counts, Qg);
    k_rows<<<dim3(NH * CC / CG), dim3(256), 0, stream>>>(Kt, V, Qg, topi, abk, Vg);
    k_out<<<dim3(NH * LQ / 4), dim3(256), 0, stream>>>(Q, K, V, clusters, topi, abk, Vg, out);
}

// Round 14
// 421.404 us; speedup vs baseline: 6.2548x; 1.0564x over previous
//
#include <hip/hip_runtime.h>
#include <math.h>
#include <float.h>

// Problem constants (from reference)
#define NB 2
#define LQ 2048
#define HH 8
#define EE 64
#define SS 2048
#define CC 256
#define KM_ITERS 10
#define NBITS 32
#define TK 32
#define NH (NB*HH)
#define CG 4    // clusters per k_rows block

// ---------------- K1: hash bits -> 32-bit mask per (n,h,l) ----------------
__global__ __launch_bounds__(256) void k_hash(const float* __restrict__ Q,
                                              const float* __restrict__ planes,
                                              unsigned int* __restrict__ qmask) {
    int gid = blockIdx.x * 256 + threadIdx.x;      // nh*LQ + l
    int nh = gid >> 11, l = gid & (LQ - 1);
    int n = nh >> 3, h = nh & 7;
    const float* qrow = Q + (((size_t)n * LQ + l) * HH + h) * EE;
    float q[64];
    #pragma unroll
    for (int e = 0; e < 64; e++) q[e] = qrow[e];
    unsigned int m = 0;
    for (int b = 0; b < NBITS; b++) {
        double acc = (double)planes[b * 65 + 64];   // bias
        #pragma unroll
        for (int e = 0; e < 64; e++) acc += (double)q[e] * (double)planes[b * 65 + e];
        if (acc > 0.0) m |= (1u << b);
    }
    qmask[gid] = m;
}

// ---------------- K2a: centroid init ----------------
__global__ __launch_bounds__(256) void k_cinit(const unsigned int* __restrict__ qmask,
                                               unsigned int* __restrict__ cent_g) {
    int nh = blockIdx.x, t = threadIdx.x;
    cent_g[nh * CC + t] = qmask[(size_t)nh * LQ + t * 8];   // init_idx = c*8
}

// ---------------- K2b: assign (data-parallel, 128 blocks) ----------------
__global__ __launch_bounds__(256) void k_assign(const unsigned int* __restrict__ qmask,
                                                const unsigned int* __restrict__ cent_g,
                                                int* __restrict__ asg) {
    int nh = blockIdx.x >> 3;              // 8 blocks per nh
    int p = ((blockIdx.x & 7) << 8) + threadIdx.x;
    int t = threadIdx.x;
    __shared__ __align__(16) unsigned int cent[CC];
    cent[t] = cent_g[nh * CC + t];
    __syncthreads();
    unsigned int m = qmask[(size_t)nh * LQ + p];
    int best = 0x7fffffff;
    const uint4* c4p = (const uint4*)cent;
    #pragma unroll 4
    for (int c4 = 0; c4 < CC / 4; c4++) {
        uint4 cm = c4p[c4];
        int base = c4 << 2;
        int e0 = (__popc(m ^ cm.x) << 8) + base;
        int e1 = (__popc(m ^ cm.y) << 8) + base + 1;
        int e2 = (__popc(m ^ cm.z) << 8) + base + 2;
        int e3 = (__popc(m ^ cm.w) << 8) + base + 3;
        int e01 = e0 < e1 ? e0 : e1;
        int e23 = e2 < e3 ? e2 : e3;
        int e = e01 < e23 ? e01 : e23;
        best = best < e ? best : e;
    }
    asg[(size_t)nh * LQ + p] = best & 255;
}

// ---------------- K2c: update (per-nh counting sort + exact majority) ----------------
__global__ __launch_bounds__(512) void k_update(const unsigned int* __restrict__ qmask,
                                                const int* __restrict__ asg,
                                                unsigned int* __restrict__ cent_g) {
    int nh = blockIdx.x, t = threadIdx.x;
    __shared__ unsigned int sorted[LQ];               // 8KB
    __shared__ int cnts[CC], offs[CC], cursor[CC];
    if (t < CC) cnts[t] = 0;
    int bc[4]; unsigned int mym[4];
    #pragma unroll
    for (int k = 0; k < 4; k++) {
        bc[k] = asg[(size_t)nh * LQ + t + k * 512];
        mym[k] = qmask[(size_t)nh * LQ + t + k * 512];
    }
    __syncthreads();
    #pragma unroll
    for (int k = 0; k < 4; k++) atomicAdd(&cnts[bc[k]], 1);
    __syncthreads();
    if (t < 64) {                                     // single-wave exclusive scan
        int c0 = cnts[4 * t], c1 = cnts[4 * t + 1], c2 = cnts[4 * t + 2], c3 = cnts[4 * t + 3];
        int s1 = c0 + c1, s2 = s1 + c2, tot = s2 + c3;
        int inc = tot;
        #pragma unroll
        for (int o = 1; o < 64; o <<= 1) {
            int v = __shfl_up(inc, o);
            if (t >= o) inc += v;
        }
        int excl = inc - tot;
        offs[4 * t] = excl;          cursor[4 * t] = excl;
        offs[4 * t + 1] = excl + c0; cursor[4 * t + 1] = excl + c0;
        offs[4 * t + 2] = excl + s1; cursor[4 * t + 2] = excl + s1;
        offs[4 * t + 3] = excl + s2; cursor[4 * t + 3] = excl + s2;
    }
    __syncthreads();
    int cl = t >> 1, j = t & 1;
    int cnt_c = cnts[cl], off_c = offs[cl];
    #pragma unroll
    for (int k = 0; k < 4; k++) {
        int pos = atomicAdd(&cursor[bc[k]], 1);
        sorted[pos] = mym[k];
    }
    __syncthreads();
    int bs[32];
    #pragma unroll
    for (int b = 0; b < 32; b++) bs[b] = 0;
    for (int i = j; i < cnt_c; i += 2) {
        unsigned int m = sorted[off_c + i];
        #pragma unroll
        for (int b = 0; b < 32; b++) bs[b] += (m >> b) & 1;
    }
    #pragma unroll
    for (int b = 0; b < 32; b++) bs[b] += __shfl_xor(bs[b], 1);
    if (j == 0 && cnt_c > 0) {
        unsigned int nc = 0;
        #pragma unroll
        for (int b = 0; b < 32; b++) if (2 * bs[b] >= cnt_c) nc |= (1u << b);
        cent_g[nh * CC + cl] = nc;                    // exact majority; keep old if cnt==0
    }
}

// ---------------- K2d: finalize counts/offsets/order from final assignment ----------------
__global__ __launch_bounds__(512) void k_finalize(const int* __restrict__ asg,
                                                  int* __restrict__ counts_out,
                                                  int* __restrict__ order_out,
                                                  int* __restrict__ offsets_out) {
    int nh = blockIdx.x, t = threadIdx.x;
    __shared__ int cnts[CC], offs[CC], cursor[CC];
    if (t < CC) cnts[t] = 0;
    int bc[4];
    #pragma unroll
    for (int k = 0; k < 4; k++) bc[k] = asg[(size_t)nh * LQ + t + k * 512];
    __syncthreads();
    #pragma unroll
    for (int k = 0; k < 4; k++) atomicAdd(&cnts[bc[k]], 1);
    __syncthreads();
    if (t < 64) {
        int c0 = cnts[4 * t], c1 = cnts[4 * t + 1], c2 = cnts[4 * t + 2], c3 = cnts[4 * t + 3];
        int s1 = c0 + c1, s2 = s1 + c2, tot = s2 + c3;
        int inc = tot;
        #pragma unroll
        for (int o = 1; o < 64; o <<= 1) {
            int v = __shfl_up(inc, o);
            if (t >= o) inc += v;
        }
        int excl = inc - tot;
        offs[4 * t] = excl;          cursor[4 * t] = excl;
        offs[4 * t + 1] = excl + c0; cursor[4 * t + 1] = excl + c0;
        offs[4 * t + 2] = excl + s1; cursor[4 * t + 2] = excl + s1;
        offs[4 * t + 3] = excl + s2; cursor[4 * t + 3] = excl + s2;
    }
    __syncthreads();
    if (t < CC) {
        counts_out[nh * CC + t] = cnts[t];
        offsets_out[nh * CC + t] = offs[t];
    }
    #pragma unroll
    for (int k = 0; k < 4; k++) {
        int pos = atomicAdd(&cursor[bc[k]], 1);
        order_out[(size_t)nh * LQ + pos] = t + k * 512;
    }
}

// ---------------- K3: segmented cluster-mean Qg (f64), wave per cluster ----------------
__global__ __launch_bounds__(256) void k_qg(const float* __restrict__ Q,
                                            const int* __restrict__ order,
                                            const int* __restrict__ offsets,
                                            const int* __restrict__ counts,
                                            double* __restrict__ Qg) {
    int nh = blockIdx.x >> 6;              // 64 blocks per nh
    int c = (blockIdx.x & 63) * 4 + (threadIdx.x >> 6);
    int e = threadIdx.x & 63;
    int n = nh >> 3, h = nh & 7;
    int off = offsets[nh * CC + c];
    int cnt = counts[nh * CC + c];
    const int* ord = order + (size_t)nh * LQ + off;
    double acc = 0.0;
    for (int i = 0; i < cnt; i++) {
        int p = ord[i];                    // wave-uniform broadcast read
        acc += (double)Q[(((size_t)n * LQ + p) * HH + h) * EE + e];
    }
    double safe = cnt > 0 ? (double)cnt : 1.0;
    Qg[((size_t)(nh * CC + c)) * EE + e] = acc / safe;
}

// ---------------- K3b: transpose K -> Kt[nh][e][s] ----------------
__global__ __launch_bounds__(256) void k_transpose(const float* __restrict__ Kp,
                                                   float* __restrict__ Kt) {
    int nh = blockIdx.x >> 5;              // 32 s-tiles of 64
    int s0 = (blockIdx.x & 31) * 64;
    int n = nh >> 3, h = nh & 7;
    __shared__ float tile[64][65];
    int t = threadIdx.x;
    int e = t & 63, r0 = t >> 6;
    #pragma unroll
    for (int j = 0; j < 16; j++) {
        int r = r0 * 16 + j;
        tile[r][e] = Kp[(((size_t)n * SS + s0 + r) * HH + h) * EE + e];
    }
    __syncthreads();
    int sl = t & 63, eg = t >> 6;
    #pragma unroll
    for (int j = 0; j < 16; j++) {
        int ee_ = eg * 16 + j;
        Kt[((size_t)nh * EE + ee_) * SS + s0 + sl] = tile[sl][ee_];
    }
}

// ---------------- K4 v9: v2 skeleton + chunked LDS transpose (18KB) + XCD swizzle ----
// Same f64 math/decisions as v2. xrow[4][2048] (64KB) replaced by 4x 16KB chunks:
// phase A keeps acc[8][4] in regs; transpose chunk j covers s in [512j,512j+512)
// (r rows 2j,2j+1). LDS 67.5KB -> 18KB => 4 blocks/CU (was 2): double latency hiding.
// NO occupancy clamp (R7/R9 lesson); no giant unrolled staging (R12 lesson).
__global__ __launch_bounds__(256) void k_rows(const float* __restrict__ Kt,
                                              const float* __restrict__ Vp,
                                              const double* __restrict__ Qg,
                                              int* __restrict__ topi,
                                              float* __restrict__ abk,
                                              float* __restrict__ Vg) {
    int bid = blockIdx.x;
    int xcd = bid & 7, idx = bid >> 3;     // XCD-chunked: xcd owns 2 nh slices (L2-local)
    int nh = xcd * 2 + (idx >> 6);
    int cg = idx & 63;
    int c0 = cg * CG;
    int n = nh >> 3, h = nh & 7;
    int t = threadIdx.x, w = t >> 6, l = t & 63;

    __shared__ double qgl[EE][CG];         // 2KB
    __shared__ double xrowc[CG][512];      // 16KB chunk buffer (reused 4x)
    float* wbuf = (float*)&xrowc[0][0];    // [512][CG] f32 = 8KB overlay (bytes [0,8K))
    float* redv = (float*)&xrowc[2][0];    // 4KB (bytes [8K,12K), disjoint from wbuf)

    qgl[t >> 2][t & 3] = Qg[((size_t)(nh * CC + c0 + (t & 3))) * EE + (t >> 2)];
    __syncthreads();

    // ---- phase A: QK scores (f64) in registers, coalesced Kt reads (as v2) ----
    double acc[8][CG];
    #pragma unroll
    for (int r = 0; r < 8; r++)
        #pragma unroll
        for (int c = 0; c < CG; c++) acc[r][c] = 0.0;
    const float* ktb = Kt + ((size_t)nh * EE) * SS + t;
    for (int e = 0; e < EE; e++) {
        double q0 = qgl[e][0], q1 = qgl[e][1], q2 = qgl[e][2], q3 = qgl[e][3];
        const float* kr = ktb + (size_t)e * SS;
        #pragma unroll
        for (int r = 0; r < 8; r++) {
            double kv = (double)kr[r * 256];
            acc[r][0] += q0 * kv; acc[r][1] += q1 * kv;
            acc[r][2] += q2 * kv; acc[r][3] += q3 * kv;
        }
    }

    // ---- chunked transpose: acc (phase-A layout) -> v[32] (phase-B layout) ----
    // v[k] = score(c=w, s=l+64k); chunk j handles k in [8j,8j+8), s in [512j,512j+512)
    double v[32];
    #pragma unroll
    for (int j = 0; j < 4; j++) {
        __syncthreads();                   // prev chunk reads complete
        #pragma unroll
        for (int c = 0; c < CG; c++) {
            xrowc[c][t]       = acc[2 * j][c];
            xrowc[c][256 + t] = acc[2 * j + 1][c];
        }
        __syncthreads();
        #pragma unroll
        for (int m = 0; m < 8; m++)
            v[8 * j + m] = xrowc[w][((m >> 2) << 8) + ((m & 3) << 6) + l];
    }

    // ---- phase B: per-wave row (c = w): max, denom, top-32 (identical to v2) ----
    double m = v[0];
    #pragma unroll
    for (int k = 1; k < 32; k++) m = v[k] > m ? v[k] : m;
    #pragma unroll
    for (int o = 32; o > 0; o >>= 1) { double z = __shfl_xor(m, o); m = z > m ? z : m; }

    double ds = 0.0;
    #pragma unroll
    for (int k = 0; k < 32; k++) ds += (double)expf(0.125f * (float)(v[k] - m));
    #pragma unroll
    for (int o = 32; o > 0; o >>= 1) ds += __shfl_xor(ds, o);

    unsigned ext = 0;
    double lbv = -1e301; int lbi = 1 << 30;
    #pragma unroll
    for (int k = 0; k < 32; k++)
        if (v[k] > lbv) { lbv = v[k]; lbi = l + k * 64; }
    double topsum = 0.0;
    int rowid = nh * CC + c0 + w;
    for (int kk = 0; kk < TK; kk++) {
        double bv = lbv; int bi = lbi;
        #pragma unroll
        for (int o = 32; o > 0; o >>= 1) {
            double v2 = __shfl_xor(bv, o); int i2 = __shfl_xor(bi, o);
            if (v2 > bv || (v2 == bv && i2 < bi)) { bv = v2; bi = i2; }
        }
        topsum += (double)expf(0.125f * (float)(bv - m));
        if (l == 0) topi[(size_t)rowid * TK + kk] = bi;
        if ((bi & 63) == l) {
            ext |= 1u << (bi >> 6);
            lbv = -1e301; lbi = 1 << 30;
            #pragma unroll
            for (int k = 0; k < 32; k++)
                if (!((ext >> k) & 1) && v[k] > lbv) { lbv = v[k]; lbi = l + k * 64; }
        }
    }
    if (l == 0) abk[rowid] = (float)((ds - topsum) / ds);

    float invd = (float)(1.0 / ds);
    float w32r[32];
    #pragma unroll
    for (int k = 0; k < 32; k++)
        w32r[k] = ((ext >> k) & 1) ? 0.0f
                : expf(0.125f * (float)(v[k] - m)) * invd;

    // ---- phase C: chunked weight exchange + Vg accumulate ----
    // chunk j: wave w publishes weights for s in [512j,512j+512) (k=8j+m, s_loc=64m+l),
    // then computes its V partial over s in [512j+128w, 512j+128w+128), e = l.
    float a0 = 0.f, a1 = 0.f, a2 = 0.f, a3 = 0.f;
    const float* vb = Vp + (((size_t)n * SS) * HH + h) * EE + l;   // e = l
    #pragma unroll
    for (int j = 0; j < 4; j++) {
        __syncthreads();                   // prev chunk wbuf reads (or xrowc reads) done
        #pragma unroll
        for (int m2 = 0; m2 < 8; m2++)
            wbuf[(((m2 << 6) + l) << 2) + w] = w32r[8 * j + m2];
        __syncthreads();
        const float4* wp4 = (const float4*)wbuf;
        int sbase = 512 * j + 128 * w;
        for (int s = 0; s < 128; s++) {
            float4 wv = wp4[128 * w + s];                          // wave-uniform broadcast
            float vv = vb[(size_t)(sbase + s) * HH * EE];          // coalesced (e=l)
            a0 += wv.x * vv; a1 += wv.y * vv; a2 += wv.z * vv; a3 += wv.w * vv;
        }
    }
    {
        int e = l, grp = w;
        redv[(grp * 4 + 0) * 64 + e] = a0;
        redv[(grp * 4 + 1) * 64 + e] = a1;
        redv[(grp * 4 + 2) * 64 + e] = a2;
        redv[(grp * 4 + 3) * 64 + e] = a3;
        __syncthreads();
        int c = w;
        float s = redv[(0 * 4 + c) * 64 + e] + redv[(1 * 4 + c) * 64 + e]
                + redv[(2 * 4 + c) * 64 + e] + redv[(3 * 4 + c) * 64 + e];
        Vg[((size_t)(nh * CC + c0 + c)) * EE + e] = s;
    }
}

// ---------------- K5: per-query top-32 re-attention + V_bottom ----------------
__global__ __launch_bounds__(256) void k_out(const float* __restrict__ Q,
                                             const float* __restrict__ Kp,
                                             const float* __restrict__ Vp,
                                             const int* __restrict__ clusters,
                                             const int* __restrict__ topi,
                                             const float* __restrict__ abk,
                                             const float* __restrict__ Vg,
                                             float* __restrict__ out) {
    int tid = threadIdx.x, wid = tid >> 6, e = tid & 63;
    int q = blockIdx.x * 4 + wid;            // nh*LQ + l
    int nh = q >> 11, l = q & (LQ - 1);
    int n = nh >> 3, h = nh & 7;
    int c = clusters[q];
    float scale = 1.0f - abk[nh * CC + c];
    const int* ti = topi + (size_t)(nh * CC + c) * TK;
    float qe = Q[(((size_t)n * LQ + l) * HH + h) * EE + e];
    float myv = -INFINITY;
    for (int k = 0; k < TK; k++) {
        int idx = ti[k];
        float kv = Kp[(((size_t)n * SS + idx) * HH + h) * EE + e];
        float v = qe * kv;
        #pragma unroll
        for (int o = 32; o > 0; o >>= 1) v += __shfl_xor(v, o);
        if (e == k) myv = v;
    }
    float mv = myv;
    #pragma unroll
    for (int o = 32; o > 0; o >>= 1) { float v = __shfl_xor(mv, o); mv = v > mv ? v : mv; }
    float p = (e < TK) ? expf(0.125f * (myv - mv)) : 0.0f;
    float ssum = p;
    #pragma unroll
    for (int o = 32; o > 0; o >>= 1) ssum += __shfl_xor(ssum, o);
    float at = p / ssum * scale;
    float acc = 0.0f;
    for (int k = 0; k < TK; k++) {
        float wk = __shfl(at, k, 64);
        int idx = ti[k];
        acc += wk * Vp[(((size_t)n * SS + idx) * HH + h) * EE + e];
    }
    acc += Vg[(size_t)(nh * CC + c) * EE + e];
    out[(((size_t)n * LQ + l) * HH + h) * EE + e] = acc;
}

extern "C" void kernel_launch(void* const* d_in, const int* in_sizes, int n_in,
                              void* d_out, int out_size, void* d_ws, size_t ws_size,
                              hipStream_t stream) {
    const float* Q      = (const float*)d_in[0];
    const float* K      = (const float*)d_in[1];
    const float* V      = (const float*)d_in[2];
    const float* planes = (const float*)d_in[3];
    float* out = (float*)d_out;

    char* ws = (char*)d_ws;
    unsigned int* qmask    = (unsigned int*)(ws);                   // 128KB
    int*          clusters = (int*)(ws + (128 << 10));              // 128KB (= asg)
    int*          counts   = (int*)(ws + (256 << 10));              // 16KB
    float*        abk      = (float*)(ws + (272 << 10));            // 16KB
    int*          topi     = (int*)(ws + (288 << 10));              // 512KB
    float*        Vg       = (float*)(ws + (800 << 10));            // 1MB
    double*       Qg       = (double*)(ws + (1824 << 10));          // 2MB
    float*        Kt       = (float*)(ws + (4096 << 10));           // 8MB  [4MB,12MB)
    int*          order    = (int*)(ws + (12288 << 10));            // 128KB
    int*          offsets  = (int*)(ws + (12416 << 10));            // 16KB
    unsigned int* cent_g   = (unsigned int*)(ws + (12432 << 10));   // 16KB

    k_transpose<<<dim3(NH * 32), dim3(256), 0, stream>>>(K, Kt);
    k_hash<<<dim3(NH * LQ / 256), dim3(256), 0, stream>>>(Q, planes, qmask);
    k_cinit<<<dim3(NH), dim3(256), 0, stream>>>(qmask, cent_g);
    for (int it = 0; it < KM_ITERS; ++it) {
        k_assign<<<dim3(NH * 8), dim3(256), 0, stream>>>(qmask, cent_g, clusters);
        k_update<<<dim3(NH), dim3(512), 0, stream>>>(qmask, clusters, cent_g);
    }
    k_assign<<<dim3(NH * 8), dim3(256), 0, stream>>>(qmask, cent_g, clusters);
    k_finalize<<<dim3(NH), dim3(512), 0, stream>>>(clusters, counts, order, offsets);
    k_qg<<<dim3(NH * 64), dim3(256), 0, stream>>>(Q, order, offsets, counts, Qg);
    k_rows<<<dim3(NH * CC / CG), dim3(256), 0, stream>>>(Kt, V, Qg, topi, abk, Vg);
    k_out<<<dim3(NH * LQ / 4), dim3(256), 0, stream>>>(Q, K, V, clusters, topi, abk, Vg, out);
}